// Round 5
// baseline (107.598 us; speedup 1.0000x reference)
//
#include <hip/hip_runtime.h>
#include <math.h>

// BRF elementwise dynamics, fp32. out layout: [z | u_ | v_new | q_new].
// Burst-remapped: each wave owns a contiguous 512-float4 (8KB) run per stream,
// issued as 2 groups of 4 back-to-back 1KB wave-loads per stream, so the DRAM
// sees long per-stream bursts instead of 8 interleaved 1KB slices.
// Per-column coefficients precomputed once into d_ws (L2-resident).

#define DTF ((float)(1.0 / 24000.0))
#define QDECAY 0.9f

typedef float f32x4 __attribute__((ext_vector_type(4)));

__global__ void brf_coef_kernel(const float* __restrict__ omegas,
                                const float* __restrict__ bs,
                                const float* __restrict__ threshold,
                                float* __restrict__ coef, int D) {
#pragma clang fp contract(off)
    int i = blockIdx.x * blockDim.x + threadIdx.x;
    if (i < D) {
        float om = fabsf(omegas[i]);
        float t  = DTF * om;
        float tt = t * t;                 // jnp.square
        float s  = sqrtf(1.0f - tt);      // IEEE sqrt
        float p  = (-1.0f + s) / DTF;     // IEEE div
        coef[i]          = om;
        coef[D + i]      = p - fabsf(bs[i]);
        coef[2 * D + i]  = fabsf(threshold[i]);
    }
}

__device__ __forceinline__ void brf_elem(float x, float u, float v, float q,
                                         float om, float pw, float th,
                                         float& z, float& u_, float& vn, float& qn) {
#pragma clang fp contract(off)
    float b  = pw - q;                                   // (p_omega-|bs|) - q
    float t1 = (b * u) * DTF;
    float t2 = (om * v) * DTF;
    float t3 = x * DTF;
    u_ = ((u + t1) - t2) + t3;
    float t4 = (om * u) * DTF;
    float t5 = (b * v) * DTF;
    vn = (v + t4) + t5;
    float s = (fabsf(u_) - th) - q;
    z  = (s > 0.0f) ? 1.0f : 0.0f;
    qn = q * QDECAY + z;
}

#define RUN 512      // float4s per wave (contiguous run)
#define TG  4        // t-group size (4 x 1KB = 4KB burst per stream per group)

__global__ __launch_bounds__(256) void brf_burst_kernel(
        const f32x4* __restrict__ x, const f32x4* __restrict__ u,
        const f32x4* __restrict__ v, const f32x4* __restrict__ q,
        const float* __restrict__ coef, float* __restrict__ out,
        int N4, int D4, int D) {
#pragma clang fp contract(off)
    const f32x4* omv = (const f32x4*)(coef);
    const f32x4* pwv = (const f32x4*)(coef + D);
    const f32x4* thv = (const f32x4*)(coef + 2 * D);
    f32x4* out_z = (f32x4*)out;
    f32x4* out_u = out_z + (size_t)N4;
    f32x4* out_v = out_z + 2 * (size_t)N4;
    f32x4* out_q = out_z + 3 * (size_t)N4;

    const int tid  = blockIdx.x * blockDim.x + threadIdx.x;
    const int lane = tid & 63;
    const int wave = tid >> 6;
    const int base = wave * RUN + lane;
    const bool pow2 = (D4 & (D4 - 1)) == 0;

    if (base + (RUN - 64) < N4) {
        // ---- fast path: full 8-step run, grouped 2 x 4 ----
        f32x4 X[8], U[8], V[8], Q[8];
#pragma unroll
        for (int t = 0; t < TG; ++t) X[t] = __builtin_nontemporal_load(&x[base + t * 64]);
#pragma unroll
        for (int t = 0; t < TG; ++t) U[t] = __builtin_nontemporal_load(&u[base + t * 64]);
#pragma unroll
        for (int t = 0; t < TG; ++t) V[t] = __builtin_nontemporal_load(&v[base + t * 64]);
#pragma unroll
        for (int t = 0; t < TG; ++t) Q[t] = __builtin_nontemporal_load(&q[base + t * 64]);
#pragma unroll
        for (int t = TG; t < 8; ++t) X[t] = __builtin_nontemporal_load(&x[base + t * 64]);
#pragma unroll
        for (int t = TG; t < 8; ++t) U[t] = __builtin_nontemporal_load(&u[base + t * 64]);
#pragma unroll
        for (int t = TG; t < 8; ++t) V[t] = __builtin_nontemporal_load(&v[base + t * 64]);
#pragma unroll
        for (int t = TG; t < 8; ++t) Q[t] = __builtin_nontemporal_load(&q[base + t * 64]);

        f32x4 RZ[8], RU[8], RV[8], RQ[8];
#pragma unroll
        for (int t = 0; t < 8; ++t) {
            int idx = base + t * 64;
            int c4  = pow2 ? (idx & (D4 - 1)) : (idx % D4);
            f32x4 oc = omv[c4], pc = pwv[c4], tc = thv[c4];
#pragma unroll
            for (int k = 0; k < 4; ++k) {
                float z, u_, vn, qn;
                brf_elem(X[t][k], U[t][k], V[t][k], Q[t][k],
                         oc[k], pc[k], tc[k], z, u_, vn, qn);
                RZ[t][k] = z; RU[t][k] = u_; RV[t][k] = vn; RQ[t][k] = qn;
            }
        }

#pragma unroll
        for (int t = 0; t < 8; ++t) __builtin_nontemporal_store(RZ[t], &out_z[base + t * 64]);
#pragma unroll
        for (int t = 0; t < 8; ++t) __builtin_nontemporal_store(RU[t], &out_u[base + t * 64]);
#pragma unroll
        for (int t = 0; t < 8; ++t) __builtin_nontemporal_store(RV[t], &out_v[base + t * 64]);
#pragma unroll
        for (int t = 0; t < 8; ++t) __builtin_nontemporal_store(RQ[t], &out_q[base + t * 64]);
    } else {
        // ---- tail: per-step guarded ----
#pragma unroll
        for (int t = 0; t < 8; ++t) {
            int i = base + t * 64;
            if (i < N4) {
                int c4 = pow2 ? (i & (D4 - 1)) : (i % D4);
                f32x4 xv = x[i], uv = u[i], vv = v[i], qv = q[i];
                f32x4 oc = omv[c4], pc = pwv[c4], tc = thv[c4];
                f32x4 rz, ru, rv, rq;
#pragma unroll
                for (int k = 0; k < 4; ++k) {
                    float z, u_, vn, qn;
                    brf_elem(xv[k], uv[k], vv[k], qv[k], oc[k], pc[k], tc[k],
                             z, u_, vn, qn);
                    rz[k] = z; ru[k] = u_; rv[k] = vn; rq[k] = qn;
                }
                out_z[i] = rz; out_u[i] = ru; out_v[i] = rv; out_q[i] = rq;
            }
        }
    }
}

extern "C" void kernel_launch(void* const* d_in, const int* in_sizes, int n_in,
                              void* d_out, int out_size, void* d_ws, size_t ws_size,
                              hipStream_t stream) {
    const float* x   = (const float*)d_in[0];
    const float* u   = (const float*)d_in[1];
    const float* v   = (const float*)d_in[2];
    const float* q   = (const float*)d_in[3];
    const float* om  = (const float*)d_in[4];
    const float* bs  = (const float*)d_in[5];
    const float* th  = (const float*)d_in[6];
    float* out  = (float*)d_out;
    float* coef = (float*)d_ws;          // 3*D floats

    int N  = in_sizes[0];   // B*D
    int D  = in_sizes[4];
    int N4 = N / 4;
    int D4 = D / 4;

    brf_coef_kernel<<<(D + 255) / 256, 256, 0, stream>>>(om, bs, th, coef, D);

    // one wave per contiguous RUN of float4s; 4 waves (256 thr) per block
    int waves  = (N4 + RUN - 1) / RUN;
    int blocks = (waves + 3) / 4;
    brf_burst_kernel<<<blocks, 256, 0, stream>>>(
        (const f32x4*)x, (const f32x4*)u, (const f32x4*)v, (const f32x4*)q,
        coef, out, N4, D4, D);
}